// Round 15
// baseline (639.460 us; speedup 1.0000x reference)
//
#include <hip/hip_runtime.h>
#include <hip/hip_bf16.h>
#include <math.h>

// ============================================================================
// MinimalNetwork, round 15: radial merged into fused + register-group acc.
//  - radial MLP (basis->L1 VALU; L2,L3 16x16x32 MFMA) runs wave-locally inside
//    fused_kernel, in LDS aliased over sRt/sAcc (sbas over sKV). h never
//    touches global memory.
//  - consume accumulates part[2][NO] in registers across each LO group
//    (3/7/9 phases), one plain store per cell at group end: no sAcc RMW,
//    no zero-init.
//  - everything else (H-trick, b128, barrier-free phases, CSR+gather) as r14.
// ============================================================================

#define FEATD 72
#define NCOL 1216
#define SWISH_SCALE 1.679177f

typedef __attribute__((ext_vector_type(8))) short bf16x8;
typedef __attribute__((ext_vector_type(4))) float f32x4;

constexpr int NCOMBO = 19;
constexpr int CB_LO[NCOMBO] = {0,0,0,1,1,1,1,1,1,1,2,2,2,2,2,2,2,2,2};
constexpr int CB_LI[NCOMBO] = {0,1,2,0,1,1,1,2,2,2,0,1,1,1,2,2,2,2,2};
constexpr int CB_LF[NCOMBO] = {0,1,2,1,0,1,2,1,2,3,2,1,2,3,0,1,2,3,4};
constexpr int CB_OFF[NCOMBO] = {0,1,10,35,44,53,80,125,170,245,350,375,420,495,600,625,700,825,1000};
constexpr int CB_SZ[NCOMBO]  = {1,9,25,9,9,27,45,45,75,105,25,45,75,105,25,75,125,175,225};
constexpr int C3TOT = 1225;

constexpr int C3OFFT[3][3][5] = {
  { {0,-1,-1,-1,-1}, {-1,1,-1,-1,-1}, {-1,-1,10,-1,-1} },
  { {-1,35,-1,-1,-1}, {44,53,80,-1,-1}, {-1,125,170,245,-1} },
  { {-1,-1,350,-1,-1}, {-1,375,420,495,-1}, {600,625,700,825,1000} }
};
constexpr int ROFFT[3][3] = {{0,64,128},{192,256,448},{640,704,896}};
constexpr int FOFFT[3]   = {0,8,32};

__device__ const double d_fact[11] = {1.,1.,2.,6.,24.,120.,720.,5040.,40320.,362880.,3628800.};

// ---------------------------------------------------------------------------
// Wigner 3j (complex basis, Racah) + real change of basis (device, once)
// ---------------------------------------------------------------------------
__device__ double w3j_entry(int j1,int j2,int j3,int m1,int m2,int m3){
  if (m1+m2+m3 != 0) return 0.0;
  int dj = j1-j2; if (dj<0) dj=-dj;
  if (j3 < dj || j3 > j1+j2) return 0.0;
  int t1 = j2 - m1 - j3, t2 = j1 + m2 - j3;
  int kmin = 0; if (t1>kmin) kmin=t1; if (t2>kmin) kmin=t2;
  int kmax = j1+j2-j3; if (j1-m1<kmax) kmax=j1-m1; if (j2+m2<kmax) kmax=j2+m2;
  double s = 0.0;
  for (int k=kmin;k<=kmax;++k){
    double den = d_fact[k]*d_fact[k-t1]*d_fact[k-t2]*d_fact[j1+j2-j3-k]
               * d_fact[j1-m1-k]*d_fact[j2+m2-k];
    s += ((k&1)? -1.0:1.0)/den;
  }
  double pref = sqrt(d_fact[j1+j2-j3]*d_fact[j1-j2+j3]*d_fact[-j1+j2+j3]/d_fact[j1+j2+j3+1]
               * d_fact[j1+m1]*d_fact[j1-m1]*d_fact[j2+m2]*d_fact[j2-m2]
               * d_fact[j3+m3]*d_fact[j3-m3]);
  int ex = j1-j2-m3;
  if (ex & 1) pref = -pref;
  return pref*s;
}

__device__ void cob(int l, int r, int c, double& re, double& im){
  re = 0.0; im = 0.0;
  int mr = r - l, mc = c - l;
  const double s = 0.70710678118654752440;
  if (mr == 0) { if (mc == 0) re = 1.0; return; }
  if (mr > 0) {
    if (mc == mr)       re = (mr & 1) ? -s : s;
    else if (mc == -mr) re = s;
  } else {
    int m = -mr;
    if (mc == -m)      im = s;
    else if (mc == m)  im = (m & 1) ? s : -s;
  }
}

__global__ void c3_build_kernel(double* __restrict__ Tre, double* __restrict__ Tim){
  int idx = blockIdx.x*64 + threadIdx.x;
  if (idx >= C3TOT) return;
  int c = 0;
  while (c+1 < NCOMBO && idx >= CB_OFF[c+1]) ++c;
  int lo = CB_LO[c], li = CB_LI[c], lf = CB_LF[c];
  int n2 = 2*li+1, n3 = 2*lf+1;
  int loc = idx - CB_OFF[c];
  int a = loc/(n2*n3), b = (loc/n3)%n2, g = loc%n3;
  double sre=0.0, sim=0.0;
  for (int m1=-lo; m1<=lo; ++m1){
    for (int m2=-li; m2<=li; ++m2){
      int m3 = -m1-m2;
      if (m3 < -lf || m3 > lf) continue;
      double w = w3j_entry(lo,li,lf,m1,m2,m3);
      if (w == 0.0) continue;
      double r1,i1,r2,i2,r3,i3;
      cob(lo, a, m1+lo, r1,i1);
      cob(li, b, m2+li, r2,i2);
      cob(lf, g, m3+lf, r3,i3);
      double rr = r1*r2 - i1*i2, ri = r1*i2 + i1*r2;
      double fr = rr*r3 - ri*i3, fi = rr*i3 + ri*r3;
      sre += fr*w; sim += fi*w;
    }
  }
  Tre[idx] = sre; Tim[idx] = sim;
}

__global__ void c3_norm_kernel(const double* __restrict__ Tre, const double* __restrict__ Tim,
                               float* __restrict__ C3f){
  int c = blockIdx.x;
  int off = CB_OFF[c], sz = CB_SZ[c];
  int t = threadIdx.x;
  double sre=0.0, sim=0.0;
  for (int p=t; p<sz; p+=64){ double x=Tre[off+p], y=Tim[off+p]; sre+=x*x; sim+=y*y; }
  for (int m=1; m<64; m<<=1){ sre += __shfl_xor(sre, m, 64); sim += __shfl_xor(sim, m, 64); }
  bool useRe = (sre >= sim);
  double n = sqrt(useRe ? sre : sim);
  double inv = (n > 0.0) ? 1.0/n : 1.0;
  for (int p=t; p<sz; p+=64){
    double v = useRe ? Tre[off+p] : Tim[off+p];
    C3f[off+p] = (float)(v*inv);
  }
}

// ---------------------------------------------------------------------------
// W3t[c'][k] chunk-major; 0.1 folded; pitch 136, pad zeroed.
// ---------------------------------------------------------------------------
__global__ __launch_bounds__(256) void prep_w3t_kernel(const float* __restrict__ W3,
                                                       __hip_bfloat16* __restrict__ W3t){
  int idx = blockIdx.x*256 + threadIdx.x;
  if (idx >= 1216*136) return;
  int cp = idx/136, k = idx%136;
  int chunk = cp>>6, uv = cp&63;
  int lo = CB_LO[chunk], li = CB_LI[chunk], lf = CB_LF[chunk];
  int lmin = lo<li ? lo : li;
  int nlf = 2*lmin+1;
  int fi = lf - (lo>li ? lo-li : li-lo);
  int c = ROFFT[lo][li] + uv*nlf + fi;
  float v = (k < 100) ? 0.1f*W3[(size_t)k*NCOL + c] : 0.f;
  W3t[idx] = __float2bfloat16(v);
}

// Wt[o][k] = bf16(0.1*W[k][o]); rows o>=100 zero, cols k>=100 zero
__global__ __launch_bounds__(256) void prep_wt_kernel(const float* __restrict__ W,
                                                      __hip_bfloat16* __restrict__ Wt){
  int idx = blockIdx.x*256 + threadIdx.x;
  if (idx >= 112*136) return;
  int o = idx/136, k = idx%136;
  float v = (o < 100 && k < 100) ? 0.1f*W[k*100+o] : 0.f;
  Wt[idx] = __float2bfloat16(v);
}

// ---------------------------------------------------------------------------
// CSR of edges by target node
// ---------------------------------------------------------------------------
__global__ __launch_bounds__(256) void hist_kernel(const int* __restrict__ ei,
                                                   int* __restrict__ deg, int E){
  int e = blockIdx.x*256 + threadIdx.x;
  if (e < E) atomicAdd(&deg[ei[E+e]], 1);
}

__global__ __launch_bounds__(256) void scan_kernel(const int* __restrict__ deg,
                                                   int* __restrict__ off,
                                                   int* __restrict__ cursor, int N, int E){
  __shared__ int part[256], spref[256];
  const int t = threadIdx.x;
  const int CH = (N + 255)/256;
  int lo = t*CH, hi = lo+CH < N ? lo+CH : N;
  int s = 0;
  for (int n=lo; n<hi; ++n) s += deg[n];
  part[t] = s;
  __syncthreads();
  if (t == 0){
    int run = 0;
    for (int i=0;i<256;++i){ spref[i] = run; run += part[i]; }
  }
  __syncthreads();
  int run = spref[t];
  for (int n=lo; n<hi; ++n){ off[n] = run; cursor[n] = run; run += deg[n]; }
  if (t == 255) off[N] = E;
}

__global__ __launch_bounds__(256) void fill_kernel(const int* __restrict__ ei,
                                                   int* __restrict__ cursor,
                                                   int* __restrict__ eid, int E){
  int e = blockIdx.x*256 + threadIdx.x;
  if (e < E){
    int idx = atomicAdd(&cursor[ei[E+e]], 1);
    eid[idx] = e;
  }
}

// ---------------------------------------------------------------------------
// Gather: one 64-lane wave per node.
// ---------------------------------------------------------------------------
__global__ __launch_bounds__(64) void gather_kernel(const float* __restrict__ msg,
                                                    const int* __restrict__ off,
                                                    const int* __restrict__ eid,
                                                    float* __restrict__ out, int N){
  const int n = blockIdx.x;
  const int t = threadIdx.x;
  const int s = off[n], e1 = off[n+1];
  float a0 = 0.f, a1 = 0.f;
  for (int i=s; i<e1; ++i){
    const float* m = msg + (size_t)eid[i]*FEATD;
    a0 += m[t];
    if (t < 8) a1 += m[64+t];
  }
  out[(size_t)n*FEATD + t] = a0;
  if (t < 8) out[(size_t)n*FEATD + 64 + t] = a1;
}

// ---------------------------------------------------------------------------
// Fused radial + GEMM + TP. 256 thr = 4 waves; 64 edges/block;
// wave owns edges [16wv,16wv+16); role r owns u-rows {2r,2r+1}.
// ---------------------------------------------------------------------------
constexpr int OF_RT  = 0;         // 64*68 f32 = 17408 (radial sA aliases here)
constexpr int OF_ACC = 17408;     // 64*72 f32 = 18432 (radial sB aliases here)
constexpr int OF_F   = 35840;     // 64*76 f32 = 19456
constexpr int OF_RSH = 55296;     // 64*25 f32 = 6400
constexpr int OF_KV  = 61696;     // 64*26 f32 = 6656 (radial sbas aliases here)
constexpr int OF_C3  = 68352;     // 1225 f32 = 4900
constexpr int OF_SRC = 73252;     // 64 int = 256
constexpr int SMEM_SZ = 73508;    // 73.5 KB -> 2 blocks/CU

__device__ __forceinline__ float swishf(float s){
  return SWISH_SCALE * s / (1.f + __expf(-s));
}

// one radial MFMA layer (wave-local rows): sOut = swish(sIn @ Wt^T), bf16
__device__ __forceinline__ void radial_layer_mfma(
    const __hip_bfloat16* __restrict__ sIn, const __hip_bfloat16* __restrict__ Wt,
    __hip_bfloat16* __restrict__ sOut, int wv, int lr, int lq)
{
  bf16x8 bf[4];
  #pragma unroll
  for (int ks=0; ks<4; ++ks)
    bf[ks] = *(const bf16x8*)&sIn[(wv*16+lr)*136 + ks*32 + lq*8];
  f32x4 acc[7] = {};
  #pragma unroll
  for (int ks=0; ks<4; ++ks)
    #pragma unroll
    for (int ot=0; ot<7; ++ot){
      bf16x8 a = *(const bf16x8*)&Wt[(ot*16+lr)*136 + ks*32 + lq*8];
      acc[ot] = __builtin_amdgcn_mfma_f32_16x16x32_bf16(a, bf[ks], acc[ot], 0, 0, 0);
    }
  #pragma unroll
  for (int ot=0; ot<7; ++ot){
    __hip_bfloat16 hv[4];
    #pragma unroll
    for (int r=0; r<4; ++r)
      hv[r] = __float2bfloat16(swishf(acc[ot][r]));
    *(short4*)&sOut[(wv*16+lr)*136 + ot*16 + lq*4] = *(short4*)hv;
  }
  // zero k=112..127 of own rows completely (16 rows x 4 short4 quarters)
  {
    int lane = lq*16 + lr;
    int row = lane & 15, q = lane >> 4;
    short4 z = {0,0,0,0};
    *(short4*)&sOut[(wv*16+row)*136 + 112 + q*4] = z;
  }
}

template<int LO,int LI,int LF>
__device__ __forceinline__ void phase(
    int chunk, const __hip_bfloat16* __restrict__ W3t, const bf16x8 (&hf)[4],
    float* sRt, float* sFf, float* sRsh, float* sKV, const float* sC3,
    float (&part)[2][2*LO+1], int t)
{
  constexpr int NO = 2*LO+1, NI = 2*LI+1, NF = 2*LF+1;
  constexpr int C3B = C3OFFT[LO][LI][LF];
  constexpr int FO  = FOFFT[LI];

  const int e = t >> 2, role = t & 3;
  const int lane = t & 63, wv = t >> 6;
  const int lr = lane & 15, lq = lane >> 4;

  // ---- 1. kv[e][o*NI+mi] = sum_mf C3 * y : quad-split (wave-local) ----
  {
    float y[NF];
    #pragma unroll
    for (int mf=0; mf<NF; ++mf) y[mf] = sRsh[e*25 + LF*LF + mf];
    for (int it = role; it < NO*NI; it += 4){
      float s = 0.f;
      #pragma unroll
      for (int mf=0; mf<NF; ++mf) s += sC3[C3B + it*NF + mf] * y[mf];
      sKV[e*26 + it] = s;
    }
  }
  // ---- 2. MFMA: Rt[e][c], A straight from global; b128 LDS stores ----
  {
    const __hip_bfloat16* wb = W3t + (size_t)chunk*64*136;
    f32x4 a4[4] = {};
    #pragma unroll
    for (int ks=0; ks<4; ++ks){
      #pragma unroll
      for (int ct=0; ct<4; ++ct){
        bf16x8 a = *(const bf16x8*)&wb[(ct*16+lr)*136 + ks*32 + lq*8];
        a4[ct] = __builtin_amdgcn_mfma_f32_16x16x32_bf16(a, hf[ks], a4[ct], 0, 0, 0);
      }
    }
    #pragma unroll
    for (int ct=0; ct<4; ++ct)
      *(f32x4*)&sRt[(wv*16 + lr)*68 + ct*16 + lq*4] = a4[ct];
  }
  __builtin_amdgcn_wave_barrier();

  // ---- 3. consume (H-trick) into register group accumulator ----
  {
    float H[2][NI];
    #pragma unroll
    for (int du=0; du<2; ++du)
      #pragma unroll
      for (int mi=0; mi<NI; ++mi) H[du][mi] = 0.f;

    #pragma unroll
    for (int vg=0; vg<2; ++vg){
      float fb[4*NI];
      #pragma unroll
      for (int p=0; p<NI; ++p)
        *(f32x4*)&fb[p*4] = *(const f32x4*)&sFf[e*76 + FO + vg*4*NI + p*4];
      #pragma unroll
      for (int du=0; du<2; ++du){
        const int u = role*2 + du;
        f32x4 rv = *(const f32x4*)&sRt[e*68 + u*8 + vg*4];
        #pragma unroll
        for (int v=0; v<4; ++v)
          #pragma unroll
          for (int mi=0; mi<NI; ++mi)
            H[du][mi] += rv[v] * fb[v*NI + mi];
      }
    }
    #pragma unroll
    for (int o=0; o<NO; ++o){
      float s0 = 0.f, s1 = 0.f;
      #pragma unroll
      for (int mi=0; mi<NI; ++mi){
        float kvv = sKV[e*26 + o*NI + mi];
        s0 += kvv * H[0][mi];
        s1 += kvv * H[1][mi];
      }
      part[0][o] += s0;
      part[1][o] += s1;
    }
  }
  __builtin_amdgcn_wave_barrier();
}

template<int LO>
__device__ __forceinline__ void group_store(float* sAcc, const float (&part)[2][2*LO+1], int t){
  const int e = t >> 2, role = t & 3;
  #pragma unroll
  for (int du=0; du<2; ++du){
    const int u = role*2 + du;
    const int base = e*72 + ((LO==0) ? u : (LO==1) ? 8 + u*3 : 32 + u*5);
    #pragma unroll
    for (int o=0; o<2*LO+1; ++o) sAcc[base + o] = part[du][o];
  }
}

__global__ __launch_bounds__(256,2) void fused_kernel(
    const float* __restrict__ feats, const int* __restrict__ ei,
    const float* __restrict__ rsh, const float* __restrict__ radii,
    const float* __restrict__ W0,
    const __hip_bfloat16* __restrict__ W1t, const __hip_bfloat16* __restrict__ W2t,
    const __hip_bfloat16* __restrict__ W3t, const float* __restrict__ C3g,
    float* __restrict__ msg, int E)
{
  __shared__ __align__(16) char smem[SMEM_SZ];
  float* sRt  = (float*)(smem + OF_RT);
  float* sAcc = (float*)(smem + OF_ACC);
  float* sFf  = (float*)(smem + OF_F);
  float* sRsh = (float*)(smem + OF_RSH);
  float* sKV  = (float*)(smem + OF_KV);
  float* sC3  = (float*)(smem + OF_C3);
  int*   sSrc = (int*)(smem + OF_SRC);
  // radial-time aliases
  __hip_bfloat16* sA = (__hip_bfloat16*)(smem + OF_RT);    // [64][136] bf16
  __hip_bfloat16* sB = (__hip_bfloat16*)(smem + OF_ACC);   // [64][136] bf16
  float* sbas = (float*)(smem + OF_KV);                    // [64][10]

  const int t = threadIdx.x;
  const int eb = blockIdx.x*64;
  const int lane = t & 63, wv = t >> 6;
  const int lr = lane & 15, lq = lane >> 4;

  // ---- prologue staging (block-striped) ----
  for (int p=t; p<64; p+=256){
    int e = eb + p;
    sSrc[p] = (e < E) ? ei[e] : 0;
  }
  for (int p=t; p<1600; p+=256){
    int el = p/25, j = p%25;
    int e = eb + el;
    sRsh[el*25 + j] = (e < E) ? rsh[(size_t)e*25 + j] : 0.f;
  }
  for (int p=t; p<C3TOT; p+=256) sC3[p] = C3g[p];
  __syncthreads();   // sSrc visible
  for (int p=t; p<64*72; p+=256){
    int el = p/72, j = p%72;
    sFf[el*76 + j] = feats[(size_t)sSrc[el]*72 + j];
  }

  // ---- radial MLP, fully wave-local (own 16 edge rows) ----
  for (int p=lane; p<160; p+=64){
    int r16 = p/10, k = p%10;
    int eg = eb + wv*16 + r16;
    float r = (eg < E) ? radii[eg] : 0.f;
    float c = 0.7f + (2.5f/9.0f)*(float)k;
    float d = (r - c) * (9.0f/2.5f);
    sbas[(wv*16+r16)*10 + k] = __expf(-d*d);
  }
  __builtin_amdgcn_wave_barrier();
  for (int p=lane; p<1600; p+=64){
    int r16 = p/100, o = p%100;
    int er = wv*16 + r16;
    float s = 0.f;
    #pragma unroll
    for (int k=0;k<10;++k) s += sbas[er*10+k]*W0[k*100+o];
    sA[er*136+o] = __float2bfloat16(swishf(s*0.3162277660168379f));  // 1/sqrt(10)
  }
  for (int p=lane; p<576; p+=64){
    int er = wv*16 + p/36, k = 100 + p%36;
    sA[er*136+k] = __float2bfloat16(0.f);
  }
  __builtin_amdgcn_wave_barrier();
  radial_layer_mfma(sA, W1t, sB, wv, lr, lq);   // h2
  __builtin_amdgcn_wave_barrier();
  radial_layer_mfma(sB, W2t, sA, wv, lr, lq);   // h3
  __builtin_amdgcn_wave_barrier();

  // ---- h fragments into registers from own LDS rows ----
  bf16x8 hf[4];
  #pragma unroll
  for (int ks=0; ks<4; ++ks)
    hf[ks] = *(const bf16x8*)&sA[(wv*16+lr)*136 + ks*32 + lq*8];
  __syncthreads();   // sFf visible; radial scratch dead; phases may reuse sRt/sAcc/sKV

  // ---- 19 phases in 3 LO groups, register accumulators ----
  {
    float p0[2][1] = {};
    phase<0,0,0>( 0, W3t, hf, sRt, sFf, sRsh, sKV, sC3, p0, t);
    phase<0,1,1>( 1, W3t, hf, sRt, sFf, sRsh, sKV, sC3, p0, t);
    phase<0,2,2>( 2, W3t, hf, sRt, sFf, sRsh, sKV, sC3, p0, t);
    group_store<0>(sAcc, p0, t);
  }
  {
    float p1[2][3] = {};
    phase<1,0,1>( 3, W3t, hf, sRt, sFf, sRsh, sKV, sC3, p1, t);
    phase<1,1,0>( 4, W3t, hf, sRt, sFf, sRsh, sKV, sC3, p1, t);
    phase<1,1,1>( 5, W3t, hf, sRt, sFf, sRsh, sKV, sC3, p1, t);
    phase<1,1,2>( 6, W3t, hf, sRt, sFf, sRsh, sKV, sC3, p1, t);
    phase<1,2,1>( 7, W3t, hf, sRt, sFf, sRsh, sKV, sC3, p1, t);
    phase<1,2,2>( 8, W3t, hf, sRt, sFf, sRsh, sKV, sC3, p1, t);
    phase<1,2,3>( 9, W3t, hf, sRt, sFf, sRsh, sKV, sC3, p1, t);
    group_store<1>(sAcc, p1, t);
  }
  {
    float p2[2][5] = {};
    phase<2,0,2>(10, W3t, hf, sRt, sFf, sRsh, sKV, sC3, p2, t);
    phase<2,1,1>(11, W3t, hf, sRt, sFf, sRsh, sKV, sC3, p2, t);
    phase<2,1,2>(12, W3t, hf, sRt, sFf, sRsh, sKV, sC3, p2, t);
    phase<2,1,3>(13, W3t, hf, sRt, sFf, sRsh, sKV, sC3, p2, t);
    phase<2,2,0>(14, W3t, hf, sRt, sFf, sRsh, sKV, sC3, p2, t);
    phase<2,2,1>(15, W3t, hf, sRt, sFf, sRsh, sKV, sC3, p2, t);
    phase<2,2,2>(16, W3t, hf, sRt, sFf, sRsh, sKV, sC3, p2, t);
    phase<2,2,3>(17, W3t, hf, sRt, sFf, sRsh, sKV, sC3, p2, t);
    phase<2,2,4>(18, W3t, hf, sRt, sFf, sRsh, sKV, sC3, p2, t);
    group_store<2>(sAcc, p2, t);
  }

  __syncthreads();   // sAcc complete across waves

  // ---- epilogue: normalize during coalesced float4 stream-out ----
  {
    const float4* sm = (const float4*)sAcc;
    float4* gm = (float4*)(msg + (size_t)eb*FEATD);
    for (int p=t; p<1152; p+=256){
      int j4 = p % 18;
      float n = (j4 < 2) ? 0.72360125f : (j4 < 8) ? 0.8204867f : 0.9341652f;
      float4 v = sm[p];
      v.x *= n; v.y *= n; v.z *= n; v.w *= n;
      gm[p] = v;
    }
  }
}

// ---------------------------------------------------------------------------
extern "C" void kernel_launch(void* const* d_in, const int* in_sizes, int n_in,
                              void* d_out, int out_size, void* d_ws, size_t ws_size,
                              hipStream_t stream)
{
  const float* feats = (const float*)d_in[0];
  const int*   ei    = (const int*)d_in[1];
  const float* radii = (const float*)d_in[2];
  const float* rsh   = (const float*)d_in[3];
  const float* W0    = (const float*)d_in[4];
  const float* W1    = (const float*)d_in[5];
  const float* W2    = (const float*)d_in[6];
  const float* W3    = (const float*)d_in[7];
  float* out = (float*)d_out;
  const int E = in_sizes[2];
  const int N = in_sizes[0]/FEATD;

  const int EPAD = ((E + 63)/64)*64;
  const int NBLK = EPAD/64;

  char* ws = (char*)d_ws;
  size_t off_b = 0;
  float*  C3f = (float*)(ws + off_b);  off_b += 8192;
  double* Tre = (double*)(ws + off_b); off_b += 12288;
  double* Tim = (double*)(ws + off_b); off_b += 12288;          // 32768
  __hip_bfloat16* W3t = (__hip_bfloat16*)(ws + off_b); off_b += 335872;
  __hip_bfloat16* W1t = (__hip_bfloat16*)(ws + off_b); off_b += 30720;   // 112*136 bf16
  __hip_bfloat16* W2t = (__hip_bfloat16*)(ws + off_b); off_b += 30720;
  float* msg = (float*)(ws + off_b);   off_b += (size_t)EPAD*FEATD*4;
  int* deg    = (int*)(ws + off_b);    off_b += (size_t)N*4;
  int* offv   = (int*)(ws + off_b);    off_b += (size_t)(N+1)*4;
  int* cursor = (int*)(ws + off_b);    off_b += (size_t)N*4;
  int* eid    = (int*)(ws + off_b);    off_b += (size_t)E*4;

  // constants / tables
  c3_build_kernel<<<dim3((C3TOT+63)/64), dim3(64), 0, stream>>>(Tre, Tim);
  c3_norm_kernel<<<dim3(NCOMBO), dim3(64), 0, stream>>>(Tre, Tim, C3f);
  prep_w3t_kernel<<<dim3((1216*136+255)/256), dim3(256), 0, stream>>>(W3, W3t);
  prep_wt_kernel<<<dim3((112*136+255)/256), dim3(256), 0, stream>>>(W1, W1t);
  prep_wt_kernel<<<dim3((112*136+255)/256), dim3(256), 0, stream>>>(W2, W2t);

  // CSR of edges by target
  hipMemsetAsync(deg, 0, (size_t)N*4, stream);
  hist_kernel<<<dim3((E+255)/256), dim3(256), 0, stream>>>(ei, deg, E);
  scan_kernel<<<dim3(1), dim3(256), 0, stream>>>(deg, offv, cursor, N, E);
  fill_kernel<<<dim3((E+255)/256), dim3(256), 0, stream>>>(ei, cursor, eid, E);

  // main pipeline (radial merged into fused)
  fused_kernel<<<dim3(NBLK), dim3(256), 0, stream>>>(feats, ei, rsh, radii, W0,
                                                     W1t, W2t, W3t, C3f, msg, E);
  gather_kernel<<<dim3(N), dim3(64), 0, stream>>>(msg, offv, eid, out, N);
}